// Round 12
// baseline (368.799 us; speedup 1.0000x reference)
//
#include <hip/hip_runtime.h>

// GCN 3-layer, CSR-gather, low-rank L1 + fused L2/L3 transform.
//   deg+rank atomic histogram (~75us = 1.6M random-line RMW, floor) + T1 tail ->
//   scan -> fill: ONE int4 scatter/edge: edge_rec[pos]={src,label,out_norm,0} ->
//   L1 fused: h1s[n] = relu(in_norm*sum_e w_e*T1[lbl_e] + b1)*out_norm  (linear stream)
//   L2 agg:  agg = in_norm * gather(h1s)  [src from edge_rec.x]
//   L2+L3 fused GEMM: in_s LDS only (25.7KB -> ~5 blocks/CU); W2/W3 read from
//     global (L1-resident 36/19KB). Scalar LDS reads (vector+switch spilled in R9).
//   out = in_norm*gather(t, stride 52) + b3
#define N_NODES 50000
#define N_EDGES 800000
#define EMB     64
#define HID     96
#define NLAB    50
#define NB_SCAN ((N_NODES + 255) / 256)    // 196
#define TSTRIDE 52                         // padded row stride of t (float4-able)
#define EDGEB   ((N_EDGES + 255) / 256)    // 3125
#define T1B     ((NLAB * HID + 255) / 256) // 19

// Histogram both degrees; rank[i] = old count of dst bucket. Tail blocks (VALU
// idle here - atomic-bound) compute T1 = emb@W1.
__global__ void deg_rank_t1_kernel(const int* __restrict__ src, const int* __restrict__ dst,
                                   int* __restrict__ deg_out, int* __restrict__ deg_in,
                                   int* __restrict__ rank,
                                   const float* __restrict__ emb, const float* __restrict__ W1,
                                   float* __restrict__ T1) {
    int b = blockIdx.x;
    if (b < EDGEB) {
        int i = b * 256 + threadIdx.x;
        if (i < N_EDGES) {
            atomicAdd(&deg_out[src[i]], 1);
            rank[i] = atomicAdd(&deg_in[dst[i]], 1);
        }
    } else {
        int i = (b - EDGEB) * 256 + threadIdx.x;
        if (i < NLAB * HID) {
            int l = i / HID, j = i - l * HID;
            float sum = 0.0f;
#pragma unroll
            for (int k = 0; k < EMB; ++k) sum += emb[l * EMB + k] * W1[k * HID + j];
            T1[i] = sum;
        }
    }
}

// --- block sums of deg_in ---
__global__ void scan1_kernel(const int* __restrict__ deg, int* __restrict__ bsum) {
    __shared__ int s[256];
    int t = threadIdx.x, i = blockIdx.x * 256 + t;
    s[t] = (i < N_NODES) ? deg[i] : 0;
    for (int off = 128; off > 0; off >>= 1) {
        __syncthreads();
        if (t < off) s[t] += s[t + off];
    }
    if (t == 0) bsum[blockIdx.x] = s[0];
}

// Merged scan2+scan3: each block derives its prefix from bsum, scans its chunk,
// and emits norms + node_info.
__global__ void scan23_kernel(const int* __restrict__ deg_in, const int* __restrict__ bsum,
                              const int* __restrict__ deg_out, const int* __restrict__ labels,
                              int* __restrict__ row_off,
                              float* __restrict__ out_norm, float* __restrict__ in_norm,
                              int2* __restrict__ node_info) {
    __shared__ int pb[256];
    __shared__ int s[256];
    int t = threadIdx.x, i = blockIdx.x * 256 + t;
    pb[t] = (t < (int)blockIdx.x) ? bsum[t] : 0;   // blockIdx.x <= 195 < 196 entries
    int own = (i < N_NODES) ? deg_in[i] : 0;
    s[t] = own;
    __syncthreads();
    for (int off = 128; off > 0; off >>= 1) {
        if (t < off) pb[t] += pb[t + off];
        __syncthreads();
    }
    int base = pb[0];
    for (int off = 1; off < 256; off <<= 1) {
        int v = s[t];
        if (t >= off) v += s[t - off];
        __syncthreads();
        s[t] = v;
        __syncthreads();
    }
    if (i < N_NODES) {
        row_off[i] = base + s[t] - own;
        float on = rsqrtf(fmaxf((float)deg_out[i], 1.0f));
        out_norm[i] = on;
        in_norm[i]  = rsqrtf(fmaxf((float)own, 1.0f));
        node_info[i] = make_int2(labels[i], __float_as_int(on));
    }
}

// Atomic-free CSR fill: ONE 16B scatter per edge.
__global__ void fill_kernel(const int* __restrict__ src, const int* __restrict__ dst,
                            const int* __restrict__ row_off, const int* __restrict__ rank,
                            const int2* __restrict__ node_info,
                            int4* __restrict__ edge_rec) {
    int i = blockIdx.x * blockDim.x + threadIdx.x;
    if (i < N_EDGES) {
        int s = src[i];
        int2 ni = node_info[s];
        int pos = row_off[dst[i]] + rank[i];
        edge_rec[pos] = make_int4(s, ni.x, ni.y, 0);
    }
}

// Fused layer 1: 2 float4 chunks per thread, unroll-4 edges; edge_rec read linearly.
// h1s[n,:] = relu(in_norm[n]*sum_e w_e*T1[lbl_e] + b1) * out_norm[n]
__global__ void gather1t_kernel(const int4* __restrict__ edge_rec, const float* __restrict__ T1,
                                const int* __restrict__ row_off, const int* __restrict__ deg,
                                const float* __restrict__ in_norm,
                                const float* __restrict__ out_norm, const float* __restrict__ b1,
                                float* __restrict__ h1s) {
    constexpr int C = HID / 8;   // 12 chunk-pairs per node
    int i = blockIdx.x * blockDim.x + threadIdx.x;
    if (i >= N_NODES * C) return;
    int n = i / C;
    int c = i - n * C;
    const float* t1a = T1 + c * 4;
    const float* t1b = T1 + (c + C) * 4;
    int k = row_off[n];
    int e = k + deg[n];
    float ax = 0.f, ay = 0.f, az = 0.f, aw = 0.f;
    float bx = 0.f, by = 0.f, bz = 0.f, bw = 0.f;
    for (; k + 3 < e; k += 4) {
        int4 i0 = edge_rec[k];
        int4 i1 = edge_rec[k + 1];
        int4 i2 = edge_rec[k + 2];
        int4 i3 = edge_rec[k + 3];
        int r0 = i0.y * HID, r1 = i1.y * HID, r2 = i2.y * HID, r3 = i3.y * HID;
        float4 aA = *(const float4*)(t1a + r0); float4 bA = *(const float4*)(t1b + r0);
        float4 aB = *(const float4*)(t1a + r1); float4 bB = *(const float4*)(t1b + r1);
        float4 aC = *(const float4*)(t1a + r2); float4 bC = *(const float4*)(t1b + r2);
        float4 aD = *(const float4*)(t1a + r3); float4 bD = *(const float4*)(t1b + r3);
        float w0 = __int_as_float(i0.z), w1 = __int_as_float(i1.z);
        float w2 = __int_as_float(i2.z), w3 = __int_as_float(i3.z);
        ax += aA.x * w0 + aB.x * w1 + aC.x * w2 + aD.x * w3;
        ay += aA.y * w0 + aB.y * w1 + aC.y * w2 + aD.y * w3;
        az += aA.z * w0 + aB.z * w1 + aC.z * w2 + aD.z * w3;
        aw += aA.w * w0 + aB.w * w1 + aC.w * w2 + aD.w * w3;
        bx += bA.x * w0 + bB.x * w1 + bC.x * w2 + bD.x * w3;
        by += bA.y * w0 + bB.y * w1 + bC.y * w2 + bD.y * w3;
        bz += bA.z * w0 + bB.z * w1 + bC.z * w2 + bD.z * w3;
        bw += bA.w * w0 + bB.w * w1 + bC.w * w2 + bD.w * w3;
    }
    for (; k < e; ++k) {
        int4 i0 = edge_rec[k];
        int r0 = i0.y * HID;
        float4 aA = *(const float4*)(t1a + r0); float4 bA = *(const float4*)(t1b + r0);
        float w0 = __int_as_float(i0.z);
        ax += aA.x * w0; ay += aA.y * w0; az += aA.z * w0; aw += aA.w * w0;
        bx += bA.x * w0; by += bA.y * w0; bz += bA.z * w0; bw += bA.w * w0;
    }
    float nn = in_norm[n];
    float on = out_norm[n];
    float4 b1a = *(const float4*)(b1 + c * 4);
    float4 b1b = *(const float4*)(b1 + (c + C) * 4);
    float4 rA, rB;
    rA.x = fmaxf(ax * nn + b1a.x, 0.f) * on; rA.y = fmaxf(ay * nn + b1a.y, 0.f) * on;
    rA.z = fmaxf(az * nn + b1a.z, 0.f) * on; rA.w = fmaxf(aw * nn + b1a.w, 0.f) * on;
    rB.x = fmaxf(bx * nn + b1b.x, 0.f) * on; rB.y = fmaxf(by * nn + b1b.y, 0.f) * on;
    rB.z = fmaxf(bz * nn + b1b.z, 0.f) * on; rB.w = fmaxf(bw * nn + b1b.w, 0.f) * on;
    float* op = h1s + (size_t)n * HID;
    *(float4*)(op + c * 4) = rA;
    *(float4*)(op + (c + C) * 4) = rB;
}

// Layer-2 aggregate: 2 float4 chunks per thread, unroll-4 edges; src = edge_rec.x.
__global__ void gather4x2_kernel(const float* __restrict__ hs, const int* __restrict__ row_off,
                                 const int* __restrict__ deg, const int* __restrict__ erec,
                                 const float* __restrict__ in_norm, float* __restrict__ out) {
    constexpr int C = HID / 8;   // 12
    int i = blockIdx.x * blockDim.x + threadIdx.x;
    if (i >= N_NODES * C) return;
    int n = i / C;
    int c = i - n * C;
    const float* p0 = hs + c * 4;
    const float* p1 = hs + (c + C) * 4;
    int k = row_off[n];
    int e = k + deg[n];
    float ax = 0.f, ay = 0.f, az = 0.f, aw = 0.f;
    float bx = 0.f, by = 0.f, bz = 0.f, bw = 0.f;
    for (; k + 3 < e; k += 4) {
        size_t r0 = (size_t)erec[(k) * 4] * HID,     r1 = (size_t)erec[(k + 1) * 4] * HID;
        size_t r2 = (size_t)erec[(k + 2) * 4] * HID, r3 = (size_t)erec[(k + 3) * 4] * HID;
        float4 aA = *(const float4*)(p0 + r0); float4 bA = *(const float4*)(p1 + r0);
        float4 aB = *(const float4*)(p0 + r1); float4 bB = *(const float4*)(p1 + r1);
        float4 aC = *(const float4*)(p0 + r2); float4 bC = *(const float4*)(p1 + r2);
        float4 aD = *(const float4*)(p0 + r3); float4 bD = *(const float4*)(p1 + r3);
        ax += (aA.x + aB.x) + (aC.x + aD.x); ay += (aA.y + aB.y) + (aC.y + aD.y);
        az += (aA.z + aB.z) + (aC.z + aD.z); aw += (aA.w + aB.w) + (aC.w + aD.w);
        bx += (bA.x + bB.x) + (bC.x + bD.x); by += (bA.y + bB.y) + (bC.y + bD.y);
        bz += (bA.z + bB.z) + (bC.z + bD.z); bw += (bA.w + bB.w) + (bC.w + bD.w);
    }
    for (; k < e; ++k) {
        size_t r0 = (size_t)erec[k * 4] * HID;
        float4 aA = *(const float4*)(p0 + r0); float4 bA = *(const float4*)(p1 + r0);
        ax += aA.x; ay += aA.y; az += aA.z; aw += aA.w;
        bx += bA.x; by += bA.y; bz += bA.z; bw += bA.w;
    }
    float nn = in_norm[n];
    float4 rA, rB;
    rA.x = ax * nn; rA.y = ay * nn; rA.z = az * nn; rA.w = aw * nn;
    rB.x = bx * nn; rB.y = by * nn; rB.z = bz * nn; rB.w = bw * nn;
    float* op = out + (size_t)n * HID;
    *(float4*)(op + c * 4) = rA;
    *(float4*)(op + (c + C) * 4) = rB;
}

// Fused layers 2+3, LDS diet: only the 64-node tile lives in LDS (25.7KB ->
// ~5 blocks/CU vs 2 with W_s). W2 (36.9KB) and W3 (19.2KB) are read straight
// from global: L1-resident, broadcast-friendly (wave reads 384B/k).
// h2 = relu(agg@W2+b2)*out_norm kept in LDS; t = h2@W3 (stride TSTRIDE).
__global__ __launch_bounds__(256) void linear23_kernel(
        const float* __restrict__ agg, const float* __restrict__ W2,
        const float* __restrict__ b2, const float* __restrict__ out_norm,
        const float* __restrict__ W3, float* __restrict__ t) {
    constexpr int INP = 100;             // float4-aligned row stride, bank shift 4/row
    __shared__ float in_s[64][INP];      // 25.6 KB — the only LDS
    const int tid = threadIdx.x;
    const int n0 = blockIdx.x * 64;

    for (int idx = tid; idx < 64 * (HID / 4); idx += 256) {
        int m = idx / (HID / 4), c = idx - m * (HID / 4);
        int n = n0 + m;
        float4 v = (n < N_NODES) ? *(const float4*)(agg + (size_t)n * HID + c * 4)
                                 : make_float4(0.f, 0.f, 0.f, 0.f);
        *(float4*)(&in_s[m][c * 4]) = v;
    }
    __syncthreads();

    const int tx = tid & 15, ty = tid >> 4;
    const int j0 = tx * 6, m0 = ty * 4;

    // GEMM1: 64x96 @ 96x96; w from global (L1-hot), a from LDS (scalar reads)
    float acc[4][6];
#pragma unroll
    for (int i = 0; i < 4; ++i)
#pragma unroll
        for (int jj = 0; jj < 6; ++jj) acc[i][jj] = 0.0f;
#pragma unroll 4
    for (int k = 0; k < HID; ++k) {
        float a[4];
#pragma unroll
        for (int i = 0; i < 4; ++i) a[i] = in_s[m0 + i][k];
        const float* wr = W2 + k * HID + j0;
        float2 w01 = *(const float2*)(wr);
        float2 w23 = *(const float2*)(wr + 2);
        float2 w45 = *(const float2*)(wr + 4);
#pragma unroll
        for (int i = 0; i < 4; ++i) {
            acc[i][0] += a[i] * w01.x; acc[i][1] += a[i] * w01.y;
            acc[i][2] += a[i] * w23.x; acc[i][3] += a[i] * w23.y;
            acc[i][4] += a[i] * w45.x; acc[i][5] += a[i] * w45.y;
        }
    }
    __syncthreads();   // all GEMM1 reads of in_s complete

    // h2 tile -> in_s (in place); bias from global (L1)
    float2 b01 = *(const float2*)(b2 + j0);
    float2 b23 = *(const float2*)(b2 + j0 + 2);
    float2 b45 = *(const float2*)(b2 + j0 + 4);
#pragma unroll
    for (int i = 0; i < 4; ++i) {
        int n = n0 + m0 + i;
        float on = (n < N_NODES) ? out_norm[n] : 0.0f;
        in_s[m0 + i][j0 + 0] = fmaxf(acc[i][0] + b01.x, 0.0f) * on;
        in_s[m0 + i][j0 + 1] = fmaxf(acc[i][1] + b01.y, 0.0f) * on;
        in_s[m0 + i][j0 + 2] = fmaxf(acc[i][2] + b23.x, 0.0f) * on;
        in_s[m0 + i][j0 + 3] = fmaxf(acc[i][3] + b23.y, 0.0f) * on;
        in_s[m0 + i][j0 + 4] = fmaxf(acc[i][4] + b45.x, 0.0f) * on;
        in_s[m0 + i][j0 + 5] = fmaxf(acc[i][5] + b45.y, 0.0f) * on;
    }
    __syncthreads();

    // GEMM2: 64x96 @ 96x(50 padded to 64); w from global with j<NLAB predicate
    const int j20 = tx * 4;
    float acc2[4][4];
#pragma unroll
    for (int i = 0; i < 4; ++i)
#pragma unroll
        for (int jj = 0; jj < 4; ++jj) acc2[i][jj] = 0.0f;
    if (j20 < NLAB) {   // tx >= 13 would be all-pad columns; skip their GEMM
#pragma unroll 4
        for (int k = 0; k < HID; ++k) {
            float a[4];
#pragma unroll
            for (int i = 0; i < 4; ++i) a[i] = in_s[m0 + i][k];
            const float* wr = W3 + k * NLAB + j20;
            float w0 = wr[0];
            float w1 = (j20 + 1 < NLAB) ? wr[1] : 0.0f;
            float w2 = (j20 + 2 < NLAB) ? wr[2] : 0.0f;
            float w3 = (j20 + 3 < NLAB) ? wr[3] : 0.0f;
#pragma unroll
            for (int i = 0; i < 4; ++i) {
                acc2[i][0] += a[i] * w0; acc2[i][1] += a[i] * w1;
                acc2[i][2] += a[i] * w2; acc2[i][3] += a[i] * w3;
            }
        }
    }
#pragma unroll
    for (int i = 0; i < 4; ++i) {
        int n = n0 + m0 + i;
        if (n >= N_NODES) break;
#pragma unroll
        for (int jj = 0; jj < 4; ++jj) {
            int j = j20 + jj;
            if (j < TSTRIDE) t[(size_t)n * TSTRIDE + j] = acc2[i][jj];
        }
    }
}

// Final gather over t (stride 52): out[n,:50] = in_norm[n]*sum t[src] + b3.
__global__ void gather_out_kernel(const float* __restrict__ t, const int* __restrict__ row_off,
                                  const int* __restrict__ deg, const int* __restrict__ erec,
                                  const float* __restrict__ in_norm, const float* __restrict__ bias,
                                  float* __restrict__ out) {
    constexpr int C = TSTRIDE / 4;  // 13
    int i = blockIdx.x * blockDim.x + threadIdx.x;
    if (i >= N_NODES * C) return;
    int n = i / C;
    int c = i - n * C;
    int k = row_off[n];
    int e = k + deg[n];
    float ax = 0.f, ay = 0.f, az = 0.f, aw = 0.f;
    for (; k + 3 < e; k += 4) {
        int s0 = erec[(k) * 4],     s1 = erec[(k + 1) * 4];
        int s2 = erec[(k + 2) * 4], s3 = erec[(k + 3) * 4];
        float4 v0 = *(const float4*)(t + (size_t)s0 * TSTRIDE + c * 4);
        float4 v1 = *(const float4*)(t + (size_t)s1 * TSTRIDE + c * 4);
        float4 v2 = *(const float4*)(t + (size_t)s2 * TSTRIDE + c * 4);
        float4 v3 = *(const float4*)(t + (size_t)s3 * TSTRIDE + c * 4);
        ax += (v0.x + v1.x) + (v2.x + v3.x);
        ay += (v0.y + v1.y) + (v2.y + v3.y);
        az += (v0.z + v1.z) + (v2.z + v3.z);
        aw += (v0.w + v1.w) + (v2.w + v3.w);
    }
    for (; k < e; ++k) {
        int s0 = erec[k * 4];
        float4 v0 = *(const float4*)(t + (size_t)s0 * TSTRIDE + c * 4);
        ax += v0.x; ay += v0.y; az += v0.z; aw += v0.w;
    }
    float nn = in_norm[n];
    int j = c * 4;
    float* op = out + (size_t)n * NLAB + j;   // rows 8B-aligned only -> float2 stores
    float2 lo; lo.x = ax * nn + bias[j];     lo.y = ay * nn + bias[j + 1];
    *(float2*)op = lo;
    if (j + 2 < NLAB) {
        float2 hi; hi.x = az * nn + bias[j + 2]; hi.y = aw * nn + bias[j + 3];
        *(float2*)(op + 2) = hi;
    }
}

static inline int cdiv(long a, int b) { return (int)((a + b - 1) / b); }

extern "C" void kernel_launch(void* const* d_in, const int* in_sizes, int n_in,
                              void* d_out, int out_size, void* d_ws, size_t ws_size,
                              hipStream_t stream) {
    const int*   dep_labels = (const int*)d_in[0];
    const int*   src        = (const int*)d_in[1];
    const int*   dst        = (const int*)d_in[2];
    const float* emb        = (const float*)d_in[3];
    const float* W1 = (const float*)d_in[4]; const float* b1 = (const float*)d_in[5];
    const float* W2 = (const float*)d_in[6]; const float* b2 = (const float*)d_in[7];
    const float* W3 = (const float*)d_in[8]; const float* b3 = (const float*)d_in[9];
    float* out = (float*)d_out;

    // ---- workspace layout ----
    int* wsp        = (int*)d_ws;
    int* deg_out_i  = wsp;                 wsp += N_NODES;
    int* deg_in_i   = wsp;                 wsp += N_NODES;
    int* row_off    = wsp;                 wsp += N_NODES;
    int* rank       = wsp;                 wsp += N_EDGES;
    int* bsum       = wsp;                 wsp += 256;
    float* out_norm = (float*)wsp;         wsp += N_NODES;
    float* in_norm  = (float*)wsp;         wsp += N_NODES;
    int2* node_info = (int2*)wsp;          wsp += 2 * N_NODES;
    float* T1       = (float*)wsp;         wsp += NLAB * HID + 2;  // keep int4 alignment
    int4* edge_rec  = (int4*)wsp;          wsp += 4 * N_EDGES;     // 12.8 MB
    float* bufA     = (float*)wsp;         wsp += (size_t)N_NODES * HID;   // agg
    float* bufB     = (float*)wsp;         // h1s, then t (N_NODES*HID)

    const int B = 256;
    const int NLIN = cdiv(N_NODES, 64);    // 782

    hipMemsetAsync(deg_out_i, 0, 2 * N_NODES * sizeof(int), stream);
    deg_rank_t1_kernel<<<EDGEB + T1B, B, 0, stream>>>(src, dst, deg_out_i, deg_in_i, rank,
                                                      emb, W1, T1);

    scan1_kernel<<<NB_SCAN, 256, 0, stream>>>(deg_in_i, bsum);
    scan23_kernel<<<NB_SCAN, 256, 0, stream>>>(deg_in_i, bsum, deg_out_i, dep_labels,
                                               row_off, out_norm, in_norm, node_info);
    fill_kernel<<<EDGEB, B, 0, stream>>>(src, dst, row_off, rank, node_info, edge_rec);

    // Layer 1 fused: linear edge_rec stream, T1 L1-resident -> h1s
    gather1t_kernel<<<cdiv((long)N_NODES * (HID / 8), B), B, 0, stream>>>(
        edge_rec, T1, row_off, deg_in_i, in_norm, out_norm, b1, bufB);

    // Layer 2 aggregate -> agg
    gather4x2_kernel<<<cdiv((long)N_NODES * (HID / 8), B), B, 0, stream>>>(
        bufB, row_off, deg_in_i, (const int*)edge_rec, in_norm, bufA);

    // Layers 2+3 fused transform: agg -> t (h2 stays in LDS)
    linear23_kernel<<<NLIN, 256, 0, stream>>>(bufA, W2, b2, out_norm, W3, bufB);

    // Final gather + bias
    gather_out_kernel<<<cdiv((long)N_NODES * (TSTRIDE / 4), B), B, 0, stream>>>(
        bufB, row_off, deg_in_i, (const int*)edge_rec, in_norm, b3, out);
}

// Round 13
// 289.258 us; speedup vs baseline: 1.2750x; 1.2750x over previous
//
#include <hip/hip_runtime.h>
#include <hip/hip_fp16.h>

// GCN 3-layer, CSR-gather, low-rank L1 + fused L2/L3 transform.
//   deg+rank atomic histogram (~75us = 1.6M device-scope RMW, floor) + T1 tail ->
//   scan -> fill: ONE int4 scatter/edge: edge_rec[pos]={src,label,out_norm,0} ->
//   L1 fused: h1s[n] = relu(in_norm*sum w_e*T1[lbl_e] + b1)*out_norm  -> FP16 rows
//   L2 agg:  agg(fp32) = in_norm * gather(h1s fp16)   [rows 192B = half the lines]
//   L2+L3 fused GEMM (W2/W3 staged in LDS — R12 proved global-W is 2.5x slower),
//     t = h2@W3 stored FP16 (stride 52, 104B rows)
//   out = in_norm*gather(t fp16) + b3      [fp32 accumulate everywhere]
#define N_NODES 50000
#define N_EDGES 800000
#define EMB     64
#define HID     96
#define NLAB    50
#define NB_SCAN ((N_NODES + 255) / 256)    // 196
#define TSTRIDE 52                         // padded row stride of t
#define EDGEB   ((N_EDGES + 255) / 256)    // 3125
#define T1B     ((NLAB * HID + 255) / 256) // 19

__device__ __forceinline__ float2 h2f(unsigned u) {
    __half2 h = *reinterpret_cast<__half2*>(&u);
    return __half22float2(h);
}
__device__ __forceinline__ unsigned f2h(float a, float b) {
    __half2 h = __floats2half2_rn(a, b);
    return *reinterpret_cast<unsigned*>(&h);
}

// Histogram both degrees; rank[i] = old count of dst bucket. Tail blocks (VALU
// idle here - atomic-bound) compute T1 = emb@W1.
__global__ void deg_rank_t1_kernel(const int* __restrict__ src, const int* __restrict__ dst,
                                   int* __restrict__ deg_out, int* __restrict__ deg_in,
                                   int* __restrict__ rank,
                                   const float* __restrict__ emb, const float* __restrict__ W1,
                                   float* __restrict__ T1) {
    int b = blockIdx.x;
    if (b < EDGEB) {
        int i = b * 256 + threadIdx.x;
        if (i < N_EDGES) {
            atomicAdd(&deg_out[src[i]], 1);
            rank[i] = atomicAdd(&deg_in[dst[i]], 1);
        }
    } else {
        int i = (b - EDGEB) * 256 + threadIdx.x;
        if (i < NLAB * HID) {
            int l = i / HID, j = i - l * HID;
            float sum = 0.0f;
#pragma unroll
            for (int k = 0; k < EMB; ++k) sum += emb[l * EMB + k] * W1[k * HID + j];
            T1[i] = sum;
        }
    }
}

// --- block sums of deg_in ---
__global__ void scan1_kernel(const int* __restrict__ deg, int* __restrict__ bsum) {
    __shared__ int s[256];
    int t = threadIdx.x, i = blockIdx.x * 256 + t;
    s[t] = (i < N_NODES) ? deg[i] : 0;
    for (int off = 128; off > 0; off >>= 1) {
        __syncthreads();
        if (t < off) s[t] += s[t + off];
    }
    if (t == 0) bsum[blockIdx.x] = s[0];
}

// Merged scan2+scan3: each block derives its prefix from bsum, scans its chunk,
// and emits norms + node_info.
__global__ void scan23_kernel(const int* __restrict__ deg_in, const int* __restrict__ bsum,
                              const int* __restrict__ deg_out, const int* __restrict__ labels,
                              int* __restrict__ row_off,
                              float* __restrict__ out_norm, float* __restrict__ in_norm,
                              int2* __restrict__ node_info) {
    __shared__ int pb[256];
    __shared__ int s[256];
    int t = threadIdx.x, i = blockIdx.x * 256 + t;
    pb[t] = (t < (int)blockIdx.x) ? bsum[t] : 0;
    int own = (i < N_NODES) ? deg_in[i] : 0;
    s[t] = own;
    __syncthreads();
    for (int off = 128; off > 0; off >>= 1) {
        if (t < off) pb[t] += pb[t + off];
        __syncthreads();
    }
    int base = pb[0];
    for (int off = 1; off < 256; off <<= 1) {
        int v = s[t];
        if (t >= off) v += s[t - off];
        __syncthreads();
        s[t] = v;
        __syncthreads();
    }
    if (i < N_NODES) {
        row_off[i] = base + s[t] - own;
        float on = rsqrtf(fmaxf((float)deg_out[i], 1.0f));
        out_norm[i] = on;
        in_norm[i]  = rsqrtf(fmaxf((float)own, 1.0f));
        node_info[i] = make_int2(labels[i], __float_as_int(on));
    }
}

// Atomic-free CSR fill: ONE 16B scatter per edge.
__global__ void fill_kernel(const int* __restrict__ src, const int* __restrict__ dst,
                            const int* __restrict__ row_off, const int* __restrict__ rank,
                            const int2* __restrict__ node_info,
                            int4* __restrict__ edge_rec) {
    int i = blockIdx.x * blockDim.x + threadIdx.x;
    if (i < N_EDGES) {
        int s = src[i];
        int2 ni = node_info[s];
        int pos = row_off[dst[i]] + rank[i];
        edge_rec[pos] = make_int4(s, ni.x, ni.y, 0);
    }
}

// Fused layer 1: 2 float4 chunks per thread, unroll-4 edges; edge_rec read linearly.
// h1s (FP16) = relu(in_norm*sum w_e*T1[lbl_e] + b1) * out_norm
__global__ void gather1t_kernel(const int4* __restrict__ edge_rec, const float* __restrict__ T1,
                                const int* __restrict__ row_off, const int* __restrict__ deg,
                                const float* __restrict__ in_norm,
                                const float* __restrict__ out_norm, const float* __restrict__ b1,
                                __half* __restrict__ h1s) {
    constexpr int C = HID / 8;   // 12 chunk-pairs per node
    int i = blockIdx.x * blockDim.x + threadIdx.x;
    if (i >= N_NODES * C) return;
    int n = i / C;
    int c = i - n * C;
    const float* t1a = T1 + c * 4;
    const float* t1b = T1 + (c + C) * 4;
    int k = row_off[n];
    int e = k + deg[n];
    float ax = 0.f, ay = 0.f, az = 0.f, aw = 0.f;
    float bx = 0.f, by = 0.f, bz = 0.f, bw = 0.f;
    for (; k + 3 < e; k += 4) {
        int4 i0 = edge_rec[k];
        int4 i1 = edge_rec[k + 1];
        int4 i2 = edge_rec[k + 2];
        int4 i3 = edge_rec[k + 3];
        int r0 = i0.y * HID, r1 = i1.y * HID, r2 = i2.y * HID, r3 = i3.y * HID;
        float4 aA = *(const float4*)(t1a + r0); float4 bA = *(const float4*)(t1b + r0);
        float4 aB = *(const float4*)(t1a + r1); float4 bB = *(const float4*)(t1b + r1);
        float4 aC = *(const float4*)(t1a + r2); float4 bC = *(const float4*)(t1b + r2);
        float4 aD = *(const float4*)(t1a + r3); float4 bD = *(const float4*)(t1b + r3);
        float w0 = __int_as_float(i0.z), w1 = __int_as_float(i1.z);
        float w2 = __int_as_float(i2.z), w3 = __int_as_float(i3.z);
        ax += aA.x * w0 + aB.x * w1 + aC.x * w2 + aD.x * w3;
        ay += aA.y * w0 + aB.y * w1 + aC.y * w2 + aD.y * w3;
        az += aA.z * w0 + aB.z * w1 + aC.z * w2 + aD.z * w3;
        aw += aA.w * w0 + aB.w * w1 + aC.w * w2 + aD.w * w3;
        bx += bA.x * w0 + bB.x * w1 + bC.x * w2 + bD.x * w3;
        by += bA.y * w0 + bB.y * w1 + bC.y * w2 + bD.y * w3;
        bz += bA.z * w0 + bB.z * w1 + bC.z * w2 + bD.z * w3;
        bw += bA.w * w0 + bB.w * w1 + bC.w * w2 + bD.w * w3;
    }
    for (; k < e; ++k) {
        int4 i0 = edge_rec[k];
        int r0 = i0.y * HID;
        float4 aA = *(const float4*)(t1a + r0); float4 bA = *(const float4*)(t1b + r0);
        float w0 = __int_as_float(i0.z);
        ax += aA.x * w0; ay += aA.y * w0; az += aA.z * w0; aw += aA.w * w0;
        bx += bA.x * w0; by += bA.y * w0; bz += bA.z * w0; bw += bA.w * w0;
    }
    float nn = in_norm[n];
    float on = out_norm[n];
    float4 b1a = *(const float4*)(b1 + c * 4);
    float4 b1b = *(const float4*)(b1 + (c + C) * 4);
    uint2 rA, rB;
    rA.x = f2h(fmaxf(ax * nn + b1a.x, 0.f) * on, fmaxf(ay * nn + b1a.y, 0.f) * on);
    rA.y = f2h(fmaxf(az * nn + b1a.z, 0.f) * on, fmaxf(aw * nn + b1a.w, 0.f) * on);
    rB.x = f2h(fmaxf(bx * nn + b1b.x, 0.f) * on, fmaxf(by * nn + b1b.y, 0.f) * on);
    rB.y = f2h(fmaxf(bz * nn + b1b.z, 0.f) * on, fmaxf(bw * nn + b1b.w, 0.f) * on);
    __half* op = h1s + (size_t)n * HID;
    *(uint2*)(op + c * 4) = rA;
    *(uint2*)(op + (c + C) * 4) = rB;
}

// Layer-2 aggregate from FP16 rows (192B each): 2x 8B loads per edge per thread,
// unroll-4 edges, fp32 accumulation. agg written fp32.
__global__ void gather4x2_kernel(const __half* __restrict__ hs, const int* __restrict__ row_off,
                                 const int* __restrict__ deg, const int* __restrict__ erec,
                                 const float* __restrict__ in_norm, float* __restrict__ out) {
    constexpr int C = HID / 8;   // 12
    int i = blockIdx.x * blockDim.x + threadIdx.x;
    if (i >= N_NODES * C) return;
    int n = i / C;
    int c = i - n * C;
    const __half* p0 = hs + c * 4;
    const __half* p1 = hs + (c + C) * 4;
    int k = row_off[n];
    int e = k + deg[n];
    float ax = 0.f, ay = 0.f, az = 0.f, aw = 0.f;
    float bx = 0.f, by = 0.f, bz = 0.f, bw = 0.f;
    for (; k + 3 < e; k += 4) {
        size_t r0 = (size_t)erec[(k) * 4] * HID,     r1 = (size_t)erec[(k + 1) * 4] * HID;
        size_t r2 = (size_t)erec[(k + 2) * 4] * HID, r3 = (size_t)erec[(k + 3) * 4] * HID;
        uint2 aA = *(const uint2*)(p0 + r0); uint2 bA = *(const uint2*)(p1 + r0);
        uint2 aB = *(const uint2*)(p0 + r1); uint2 bB = *(const uint2*)(p1 + r1);
        uint2 aC = *(const uint2*)(p0 + r2); uint2 bC = *(const uint2*)(p1 + r2);
        uint2 aD = *(const uint2*)(p0 + r3); uint2 bD = *(const uint2*)(p1 + r3);
        float2 f;
        f = h2f(aA.x); ax += f.x; ay += f.y;  f = h2f(aA.y); az += f.x; aw += f.y;
        f = h2f(aB.x); ax += f.x; ay += f.y;  f = h2f(aB.y); az += f.x; aw += f.y;
        f = h2f(aC.x); ax += f.x; ay += f.y;  f = h2f(aC.y); az += f.x; aw += f.y;
        f = h2f(aD.x); ax += f.x; ay += f.y;  f = h2f(aD.y); az += f.x; aw += f.y;
        f = h2f(bA.x); bx += f.x; by += f.y;  f = h2f(bA.y); bz += f.x; bw += f.y;
        f = h2f(bB.x); bx += f.x; by += f.y;  f = h2f(bB.y); bz += f.x; bw += f.y;
        f = h2f(bC.x); bx += f.x; by += f.y;  f = h2f(bC.y); bz += f.x; bw += f.y;
        f = h2f(bD.x); bx += f.x; by += f.y;  f = h2f(bD.y); bz += f.x; bw += f.y;
    }
    for (; k < e; ++k) {
        size_t r0 = (size_t)erec[k * 4] * HID;
        uint2 aA = *(const uint2*)(p0 + r0); uint2 bA = *(const uint2*)(p1 + r0);
        float2 f;
        f = h2f(aA.x); ax += f.x; ay += f.y;  f = h2f(aA.y); az += f.x; aw += f.y;
        f = h2f(bA.x); bx += f.x; by += f.y;  f = h2f(bA.y); bz += f.x; bw += f.y;
    }
    float nn = in_norm[n];
    float4 rA, rB;
    rA.x = ax * nn; rA.y = ay * nn; rA.z = az * nn; rA.w = aw * nn;
    rB.x = bx * nn; rB.y = by * nn; rB.z = bz * nn; rB.w = bw * nn;
    float* op = out + (size_t)n * HID;
    *(float4*)(op + c * 4) = rA;
    *(float4*)(op + (c + C) * 4) = rB;
}

// Fused layers 2+3 (R10-proven LDS-W form): h2 = relu(agg@W2+b2)*out_norm in LDS,
// t = h2@W3 stored FP16 (stride TSTRIDE, cols 50/51 zero via zero-padded W_s).
__global__ __launch_bounds__(256) void linear23_kernel(
        const float* __restrict__ agg, const float* __restrict__ W2,
        const float* __restrict__ b2, const float* __restrict__ out_norm,
        const float* __restrict__ W3, __half* __restrict__ t) {
    constexpr int INP = 100;
    __shared__ float in_s[64][INP];      // 25.6 KB
    __shared__ float W_s[HID * HID];     // 36.9 KB ([k][j]; phase 2: 96x64)
    __shared__ float bs[HID];
    const int tid = threadIdx.x;
    const int n0 = blockIdx.x * 64;

    for (int idx = tid; idx < 64 * (HID / 4); idx += 256) {
        int m = idx / (HID / 4), c = idx - m * (HID / 4);
        int n = n0 + m;
        float4 v = (n < N_NODES) ? *(const float4*)(agg + (size_t)n * HID + c * 4)
                                 : make_float4(0.f, 0.f, 0.f, 0.f);
        *(float4*)(&in_s[m][c * 4]) = v;
    }
    for (int idx = tid; idx < HID * HID / 4; idx += 256)
        *(float4*)(&W_s[idx * 4]) = *(const float4*)(W2 + idx * 4);
    if (tid < HID) bs[tid] = b2[tid];
    __syncthreads();

    const int tx = tid & 15, ty = tid >> 4;
    const int j0 = tx * 6, m0 = ty * 4;

    // GEMM1: 64x96 @ 96x96
    float acc[4][6];
#pragma unroll
    for (int i = 0; i < 4; ++i)
#pragma unroll
        for (int jj = 0; jj < 6; ++jj) acc[i][jj] = 0.0f;
#pragma unroll 4
    for (int k = 0; k < HID; ++k) {
        float a[4], w[6];
#pragma unroll
        for (int i = 0; i < 4; ++i) a[i] = in_s[m0 + i][k];
#pragma unroll
        for (int jj = 0; jj < 6; ++jj) w[jj] = W_s[k * HID + j0 + jj];
#pragma unroll
        for (int i = 0; i < 4; ++i)
#pragma unroll
            for (int jj = 0; jj < 6; ++jj) acc[i][jj] += a[i] * w[jj];
    }
    __syncthreads();

    // h2 tile -> in_s (in place); W3 (zero-padded to 64 cols) -> W_s
#pragma unroll
    for (int i = 0; i < 4; ++i) {
        int n = n0 + m0 + i;
        float on = (n < N_NODES) ? out_norm[n] : 0.0f;
#pragma unroll
        for (int jj = 0; jj < 6; ++jj)
            in_s[m0 + i][j0 + jj] = fmaxf(acc[i][jj] + bs[j0 + jj], 0.0f) * on;
    }
    for (int idx = tid; idx < HID * 64; idx += 256) {
        int k = idx >> 6, j = idx & 63;
        W_s[idx] = (j < NLAB) ? W3[k * NLAB + j] : 0.0f;
    }
    __syncthreads();

    // GEMM2: 64x96 @ 96x64 (cols >= 50 zero)
    const int j20 = tx * 4;
    float acc2[4][4];
#pragma unroll
    for (int i = 0; i < 4; ++i)
#pragma unroll
        for (int jj = 0; jj < 4; ++jj) acc2[i][jj] = 0.0f;
#pragma unroll 4
    for (int k = 0; k < HID; ++k) {
        float a[4], w[4];
#pragma unroll
        for (int i = 0; i < 4; ++i) a[i] = in_s[m0 + i][k];
#pragma unroll
        for (int jj = 0; jj < 4; ++jj) w[jj] = W_s[k * 64 + j20 + jj];
#pragma unroll
        for (int i = 0; i < 4; ++i)
#pragma unroll
            for (int jj = 0; jj < 4; ++jj) acc2[i][jj] += a[i] * w[jj];
    }
    if (j20 < TSTRIDE) {   // tx<=12: 4 halfs (8B) per row
#pragma unroll
        for (int i = 0; i < 4; ++i) {
            int n = n0 + m0 + i;
            if (n >= N_NODES) break;
            uint2 raw;
            raw.x = f2h(acc2[i][0], acc2[i][1]);
            raw.y = f2h(acc2[i][2], acc2[i][3]);
            *(uint2*)(t + (size_t)n * TSTRIDE + j20) = raw;
        }
    }
}

// Final gather over FP16 t (104B rows): out[n,:50] = in_norm[n]*sum t[src] + b3.
__global__ void gather_out_kernel(const __half* __restrict__ t, const int* __restrict__ row_off,
                                  const int* __restrict__ deg, const int* __restrict__ erec,
                                  const float* __restrict__ in_norm, const float* __restrict__ bias,
                                  float* __restrict__ out) {
    constexpr int C = TSTRIDE / 4;  // 13
    int i = blockIdx.x * blockDim.x + threadIdx.x;
    if (i >= N_NODES * C) return;
    int n = i / C;
    int c = i - n * C;
    const __half* p0 = t + c * 4;
    int k = row_off[n];
    int e = k + deg[n];
    float ax = 0.f, ay = 0.f, az = 0.f, aw = 0.f;
    for (; k + 3 < e; k += 4) {
        size_t r0 = (size_t)erec[(k) * 4] * TSTRIDE,     r1 = (size_t)erec[(k + 1) * 4] * TSTRIDE;
        size_t r2 = (size_t)erec[(k + 2) * 4] * TSTRIDE, r3 = (size_t)erec[(k + 3) * 4] * TSTRIDE;
        uint2 v0 = *(const uint2*)(p0 + r0);
        uint2 v1 = *(const uint2*)(p0 + r1);
        uint2 v2 = *(const uint2*)(p0 + r2);
        uint2 v3 = *(const uint2*)(p0 + r3);
        float2 f;
        f = h2f(v0.x); ax += f.x; ay += f.y;  f = h2f(v0.y); az += f.x; aw += f.y;
        f = h2f(v1.x); ax += f.x; ay += f.y;  f = h2f(v1.y); az += f.x; aw += f.y;
        f = h2f(v2.x); ax += f.x; ay += f.y;  f = h2f(v2.y); az += f.x; aw += f.y;
        f = h2f(v3.x); ax += f.x; ay += f.y;  f = h2f(v3.y); az += f.x; aw += f.y;
    }
    for (; k < e; ++k) {
        size_t r0 = (size_t)erec[k * 4] * TSTRIDE;
        uint2 v0 = *(const uint2*)(p0 + r0);
        float2 f;
        f = h2f(v0.x); ax += f.x; ay += f.y;  f = h2f(v0.y); az += f.x; aw += f.y;
    }
    float nn = in_norm[n];
    int j = c * 4;
    float* op = out + (size_t)n * NLAB + j;   // rows 8B-aligned only -> float2 stores
    float2 lo; lo.x = ax * nn + bias[j];     lo.y = ay * nn + bias[j + 1];
    *(float2*)op = lo;
    if (j + 2 < NLAB) {
        float2 hi; hi.x = az * nn + bias[j + 2]; hi.y = aw * nn + bias[j + 3];
        *(float2*)(op + 2) = hi;
    }
}

static inline int cdiv(long a, int b) { return (int)((a + b - 1) / b); }

extern "C" void kernel_launch(void* const* d_in, const int* in_sizes, int n_in,
                              void* d_out, int out_size, void* d_ws, size_t ws_size,
                              hipStream_t stream) {
    const int*   dep_labels = (const int*)d_in[0];
    const int*   src        = (const int*)d_in[1];
    const int*   dst        = (const int*)d_in[2];
    const float* emb        = (const float*)d_in[3];
    const float* W1 = (const float*)d_in[4]; const float* b1 = (const float*)d_in[5];
    const float* W2 = (const float*)d_in[6]; const float* b2 = (const float*)d_in[7];
    const float* W3 = (const float*)d_in[8]; const float* b3 = (const float*)d_in[9];
    float* out = (float*)d_out;

    // ---- workspace layout ----
    int* wsp        = (int*)d_ws;
    int* deg_out_i  = wsp;                 wsp += N_NODES;
    int* deg_in_i   = wsp;                 wsp += N_NODES;
    int* row_off    = wsp;                 wsp += N_NODES;
    int* rank       = wsp;                 wsp += N_EDGES;
    int* bsum       = wsp;                 wsp += 256;
    float* out_norm = (float*)wsp;         wsp += N_NODES;
    float* in_norm  = (float*)wsp;         wsp += N_NODES;
    int2* node_info = (int2*)wsp;          wsp += 2 * N_NODES;
    float* T1       = (float*)wsp;         wsp += NLAB * HID + 2;
    int4* edge_rec  = (int4*)wsp;          wsp += 4 * N_EDGES;     // 12.8 MB
    float* bufA     = (float*)wsp;         wsp += (size_t)N_NODES * HID;   // agg (fp32)
    __half* bufH    = (__half*)wsp;        // h1s (fp16), then t (fp16)

    const int B = 256;
    const int NLIN = cdiv(N_NODES, 64);    // 782

    hipMemsetAsync(deg_out_i, 0, 2 * N_NODES * sizeof(int), stream);
    deg_rank_t1_kernel<<<EDGEB + T1B, B, 0, stream>>>(src, dst, deg_out_i, deg_in_i, rank,
                                                      emb, W1, T1);

    scan1_kernel<<<NB_SCAN, 256, 0, stream>>>(deg_in_i, bsum);
    scan23_kernel<<<NB_SCAN, 256, 0, stream>>>(deg_in_i, bsum, deg_out_i, dep_labels,
                                               row_off, out_norm, in_norm, node_info);
    fill_kernel<<<EDGEB, B, 0, stream>>>(src, dst, row_off, rank, node_info, edge_rec);

    // Layer 1 fused: linear edge_rec stream, T1 L1-resident -> h1s (fp16)
    gather1t_kernel<<<cdiv((long)N_NODES * (HID / 8), B), B, 0, stream>>>(
        edge_rec, T1, row_off, deg_in_i, in_norm, out_norm, b1, bufH);

    // Layer 2 aggregate (fp16 rows -> fp32 agg)
    gather4x2_kernel<<<cdiv((long)N_NODES * (HID / 8), B), B, 0, stream>>>(
        bufH, row_off, deg_in_i, (const int*)edge_rec, in_norm, bufA);

    // Layers 2+3 fused transform: agg -> t (fp16; h2 stays in LDS)
    linear23_kernel<<<NLIN, 256, 0, stream>>>(bufA, W2, b2, out_norm, W3, bufH);

    // Final gather + bias (fp16 t -> fp32 out)
    gather_out_kernel<<<cdiv((long)N_NODES * (TSTRIDE / 4), B), B, 0, stream>>>(
        bufH, row_off, deg_in_i, (const int*)edge_rec, in_norm, b3, out);
}

// Round 14
// 281.358 us; speedup vs baseline: 1.3108x; 1.0281x over previous
//
#include <hip/hip_runtime.h>
#include <hip/hip_fp16.h>

// GCN 3-layer, CSR-gather, low-rank L1 + fused L2/L3 transform.
//   deg+rank atomic histogram (~80us = 1.6M device-scope RMW, floor) + T1 tail ->
//   scan -> fill: ONE int2 (8B) scatter/edge: {src|label<<16, out_norm} ->
//   L1 fused: h1s(fp16) = relu(in_norm*sum w_e*T1[lbl_e] + b1)*out_norm (linear stream)
//   L2 agg:  agg(fp32) = in_norm * gather(h1s fp16, 192B rows)
//   L2+L3 fused GEMM (W2/W3 in LDS — global-W was 2.5x slower, R12),
//     t = h2@W3 stored FP16, row stride 64 halfs = 128B = exactly 1 cacheline
//   out = in_norm*gather(t fp16) + b3      [fp32 accumulate everywhere]
#define N_NODES 50000
#define N_EDGES 800000
#define EMB     64
#define HID     96
#define NLAB    50
#define NB_SCAN ((N_NODES + 255) / 256)    // 196
#define TSTRIDE 64                         // t row stride (halfs): 128B line-aligned
#define TC      13                         // gather chunks over t (cols 0..51)
#define EDGEB   ((N_EDGES + 255) / 256)    // 3125
#define T1B     ((NLAB * HID + 255) / 256) // 19

__device__ __forceinline__ float2 h2f(unsigned u) {
    __half2 h = *reinterpret_cast<__half2*>(&u);
    return __half22float2(h);
}
__device__ __forceinline__ unsigned f2h(float a, float b) {
    __half2 h = __floats2half2_rn(a, b);
    return *reinterpret_cast<unsigned*>(&h);
}

// Histogram both degrees; rank[i] = old count of dst bucket. Tail blocks (VALU
// idle here - atomic-bound) compute T1 = emb@W1.
__global__ void deg_rank_t1_kernel(const int* __restrict__ src, const int* __restrict__ dst,
                                   int* __restrict__ deg_out, int* __restrict__ deg_in,
                                   int* __restrict__ rank,
                                   const float* __restrict__ emb, const float* __restrict__ W1,
                                   float* __restrict__ T1) {
    int b = blockIdx.x;
    if (b < EDGEB) {
        int i = b * 256 + threadIdx.x;
        if (i < N_EDGES) {
            atomicAdd(&deg_out[src[i]], 1);
            rank[i] = atomicAdd(&deg_in[dst[i]], 1);
        }
    } else {
        int i = (b - EDGEB) * 256 + threadIdx.x;
        if (i < NLAB * HID) {
            int l = i / HID, j = i - l * HID;
            float sum = 0.0f;
#pragma unroll
            for (int k = 0; k < EMB; ++k) sum += emb[l * EMB + k] * W1[k * HID + j];
            T1[i] = sum;
        }
    }
}

// --- block sums of deg_in ---
__global__ void scan1_kernel(const int* __restrict__ deg, int* __restrict__ bsum) {
    __shared__ int s[256];
    int t = threadIdx.x, i = blockIdx.x * 256 + t;
    s[t] = (i < N_NODES) ? deg[i] : 0;
    for (int off = 128; off > 0; off >>= 1) {
        __syncthreads();
        if (t < off) s[t] += s[t + off];
    }
    if (t == 0) bsum[blockIdx.x] = s[0];
}

// Merged scan2+scan3: each block derives its prefix from bsum, scans its chunk,
// and emits norms + node_info (label<<16 in .x, out_norm bits in .y).
__global__ void scan23_kernel(const int* __restrict__ deg_in, const int* __restrict__ bsum,
                              const int* __restrict__ deg_out, const int* __restrict__ labels,
                              int* __restrict__ row_off,
                              float* __restrict__ out_norm, float* __restrict__ in_norm,
                              int2* __restrict__ node_info) {
    __shared__ int pb[256];
    __shared__ int s[256];
    int t = threadIdx.x, i = blockIdx.x * 256 + t;
    pb[t] = (t < (int)blockIdx.x) ? bsum[t] : 0;
    int own = (i < N_NODES) ? deg_in[i] : 0;
    s[t] = own;
    __syncthreads();
    for (int off = 128; off > 0; off >>= 1) {
        if (t < off) pb[t] += pb[t + off];
        __syncthreads();
    }
    int base = pb[0];
    for (int off = 1; off < 256; off <<= 1) {
        int v = s[t];
        if (t >= off) v += s[t - off];
        __syncthreads();
        s[t] = v;
        __syncthreads();
    }
    if (i < N_NODES) {
        row_off[i] = base + s[t] - own;
        float on = rsqrtf(fmaxf((float)deg_out[i], 1.0f));
        out_norm[i] = on;
        in_norm[i]  = rsqrtf(fmaxf((float)own, 1.0f));
        node_info[i] = make_int2(labels[i] << 16, __float_as_int(on));
    }
}

// Atomic-free CSR fill: ONE 8B scatter per edge. rec = {src|label<<16, out_norm}
__global__ void fill_kernel(const int* __restrict__ src, const int* __restrict__ dst,
                            const int* __restrict__ row_off, const int* __restrict__ rank,
                            const int2* __restrict__ node_info,
                            int2* __restrict__ edge_rec) {
    int i = blockIdx.x * blockDim.x + threadIdx.x;
    if (i < N_EDGES) {
        int s = src[i];
        int2 ni = node_info[s];
        int pos = row_off[dst[i]] + rank[i];
        edge_rec[pos] = make_int2(s | ni.x, ni.y);
    }
}

// Fused layer 1: 2 float4 chunks per thread, unroll-4 edges; edge_rec read linearly.
// h1s (FP16) = relu(in_norm*sum w_e*T1[lbl_e] + b1) * out_norm
__global__ void gather1t_kernel(const int2* __restrict__ edge_rec, const float* __restrict__ T1,
                                const int* __restrict__ row_off, const int* __restrict__ deg,
                                const float* __restrict__ in_norm,
                                const float* __restrict__ out_norm, const float* __restrict__ b1,
                                __half* __restrict__ h1s) {
    constexpr int C = HID / 8;   // 12 chunk-pairs per node
    int i = blockIdx.x * blockDim.x + threadIdx.x;
    if (i >= N_NODES * C) return;
    int n = i / C;
    int c = i - n * C;
    const float* t1a = T1 + c * 4;
    const float* t1b = T1 + (c + C) * 4;
    int k = row_off[n];
    int e = k + deg[n];
    float ax = 0.f, ay = 0.f, az = 0.f, aw = 0.f;
    float bx = 0.f, by = 0.f, bz = 0.f, bw = 0.f;
    for (; k + 3 < e; k += 4) {
        int2 i0 = edge_rec[k];
        int2 i1 = edge_rec[k + 1];
        int2 i2 = edge_rec[k + 2];
        int2 i3 = edge_rec[k + 3];
        int r0 = ((unsigned)i0.x >> 16) * HID, r1 = ((unsigned)i1.x >> 16) * HID;
        int r2 = ((unsigned)i2.x >> 16) * HID, r3 = ((unsigned)i3.x >> 16) * HID;
        float4 aA = *(const float4*)(t1a + r0); float4 bA = *(const float4*)(t1b + r0);
        float4 aB = *(const float4*)(t1a + r1); float4 bB = *(const float4*)(t1b + r1);
        float4 aC = *(const float4*)(t1a + r2); float4 bC = *(const float4*)(t1b + r2);
        float4 aD = *(const float4*)(t1a + r3); float4 bD = *(const float4*)(t1b + r3);
        float w0 = __int_as_float(i0.y), w1 = __int_as_float(i1.y);
        float w2 = __int_as_float(i2.y), w3 = __int_as_float(i3.y);
        ax += aA.x * w0 + aB.x * w1 + aC.x * w2 + aD.x * w3;
        ay += aA.y * w0 + aB.y * w1 + aC.y * w2 + aD.y * w3;
        az += aA.z * w0 + aB.z * w1 + aC.z * w2 + aD.z * w3;
        aw += aA.w * w0 + aB.w * w1 + aC.w * w2 + aD.w * w3;
        bx += bA.x * w0 + bB.x * w1 + bC.x * w2 + bD.x * w3;
        by += bA.y * w0 + bB.y * w1 + bC.y * w2 + bD.y * w3;
        bz += bA.z * w0 + bB.z * w1 + bC.z * w2 + bD.z * w3;
        bw += bA.w * w0 + bB.w * w1 + bC.w * w2 + bD.w * w3;
    }
    for (; k < e; ++k) {
        int2 i0 = edge_rec[k];
        int r0 = ((unsigned)i0.x >> 16) * HID;
        float4 aA = *(const float4*)(t1a + r0); float4 bA = *(const float4*)(t1b + r0);
        float w0 = __int_as_float(i0.y);
        ax += aA.x * w0; ay += aA.y * w0; az += aA.z * w0; aw += aA.w * w0;
        bx += bA.x * w0; by += bA.y * w0; bz += bA.z * w0; bw += bA.w * w0;
    }
    float nn = in_norm[n];
    float on = out_norm[n];
    float4 b1a = *(const float4*)(b1 + c * 4);
    float4 b1b = *(const float4*)(b1 + (c + C) * 4);
    uint2 rA, rB;
    rA.x = f2h(fmaxf(ax * nn + b1a.x, 0.f) * on, fmaxf(ay * nn + b1a.y, 0.f) * on);
    rA.y = f2h(fmaxf(az * nn + b1a.z, 0.f) * on, fmaxf(aw * nn + b1a.w, 0.f) * on);
    rB.x = f2h(fmaxf(bx * nn + b1b.x, 0.f) * on, fmaxf(by * nn + b1b.y, 0.f) * on);
    rB.y = f2h(fmaxf(bz * nn + b1b.z, 0.f) * on, fmaxf(bw * nn + b1b.w, 0.f) * on);
    __half* op = h1s + (size_t)n * HID;
    *(uint2*)(op + c * 4) = rA;
    *(uint2*)(op + (c + C) * 4) = rB;
}

// Layer-2 aggregate from FP16 rows (192B): src = edge_rec[k].x & 0xFFFF.
__global__ void gather4x2_kernel(const __half* __restrict__ hs, const int* __restrict__ row_off,
                                 const int* __restrict__ deg, const int2* __restrict__ erec,
                                 const float* __restrict__ in_norm, float* __restrict__ out) {
    constexpr int C = HID / 8;   // 12
    int i = blockIdx.x * blockDim.x + threadIdx.x;
    if (i >= N_NODES * C) return;
    int n = i / C;
    int c = i - n * C;
    const __half* p0 = hs + c * 4;
    const __half* p1 = hs + (c + C) * 4;
    int k = row_off[n];
    int e = k + deg[n];
    float ax = 0.f, ay = 0.f, az = 0.f, aw = 0.f;
    float bx = 0.f, by = 0.f, bz = 0.f, bw = 0.f;
    for (; k + 3 < e; k += 4) {
        size_t r0 = (size_t)(erec[k].x & 0xFFFF) * HID;
        size_t r1 = (size_t)(erec[k + 1].x & 0xFFFF) * HID;
        size_t r2 = (size_t)(erec[k + 2].x & 0xFFFF) * HID;
        size_t r3 = (size_t)(erec[k + 3].x & 0xFFFF) * HID;
        uint2 aA = *(const uint2*)(p0 + r0); uint2 bA = *(const uint2*)(p1 + r0);
        uint2 aB = *(const uint2*)(p0 + r1); uint2 bB = *(const uint2*)(p1 + r1);
        uint2 aC = *(const uint2*)(p0 + r2); uint2 bC = *(const uint2*)(p1 + r2);
        uint2 aD = *(const uint2*)(p0 + r3); uint2 bD = *(const uint2*)(p1 + r3);
        float2 f;
        f = h2f(aA.x); ax += f.x; ay += f.y;  f = h2f(aA.y); az += f.x; aw += f.y;
        f = h2f(aB.x); ax += f.x; ay += f.y;  f = h2f(aB.y); az += f.x; aw += f.y;
        f = h2f(aC.x); ax += f.x; ay += f.y;  f = h2f(aC.y); az += f.x; aw += f.y;
        f = h2f(aD.x); ax += f.x; ay += f.y;  f = h2f(aD.y); az += f.x; aw += f.y;
        f = h2f(bA.x); bx += f.x; by += f.y;  f = h2f(bA.y); bz += f.x; bw += f.y;
        f = h2f(bB.x); bx += f.x; by += f.y;  f = h2f(bB.y); bz += f.x; bw += f.y;
        f = h2f(bC.x); bx += f.x; by += f.y;  f = h2f(bC.y); bz += f.x; bw += f.y;
        f = h2f(bD.x); bx += f.x; by += f.y;  f = h2f(bD.y); bz += f.x; bw += f.y;
    }
    for (; k < e; ++k) {
        size_t r0 = (size_t)(erec[k].x & 0xFFFF) * HID;
        uint2 aA = *(const uint2*)(p0 + r0); uint2 bA = *(const uint2*)(p1 + r0);
        float2 f;
        f = h2f(aA.x); ax += f.x; ay += f.y;  f = h2f(aA.y); az += f.x; aw += f.y;
        f = h2f(bA.x); bx += f.x; by += f.y;  f = h2f(bA.y); bz += f.x; bw += f.y;
    }
    float nn = in_norm[n];
    float4 rA, rB;
    rA.x = ax * nn; rA.y = ay * nn; rA.z = az * nn; rA.w = aw * nn;
    rB.x = bx * nn; rB.y = by * nn; rB.z = bz * nn; rB.w = bw * nn;
    float* op = out + (size_t)n * HID;
    *(float4*)(op + c * 4) = rA;
    *(float4*)(op + (c + C) * 4) = rB;
}

// Fused layers 2+3 (LDS-W form): h2 = relu(agg@W2+b2)*out_norm in LDS,
// t = h2@W3 stored FP16 at row stride 64 halfs (128B line-aligned; cols 0..51 used).
__global__ __launch_bounds__(256) void linear23_kernel(
        const float* __restrict__ agg, const float* __restrict__ W2,
        const float* __restrict__ b2, const float* __restrict__ out_norm,
        const float* __restrict__ W3, __half* __restrict__ t) {
    constexpr int INP = 100;
    __shared__ float in_s[64][INP];      // 25.6 KB
    __shared__ float W_s[HID * HID];     // 36.9 KB ([k][j]; phase 2: 96x64)
    __shared__ float bs[HID];
    const int tid = threadIdx.x;
    const int n0 = blockIdx.x * 64;

    for (int idx = tid; idx < 64 * (HID / 4); idx += 256) {
        int m = idx / (HID / 4), c = idx - m * (HID / 4);
        int n = n0 + m;
        float4 v = (n < N_NODES) ? *(const float4*)(agg + (size_t)n * HID + c * 4)
                                 : make_float4(0.f, 0.f, 0.f, 0.f);
        *(float4*)(&in_s[m][c * 4]) = v;
    }
    for (int idx = tid; idx < HID * HID / 4; idx += 256)
        *(float4*)(&W_s[idx * 4]) = *(const float4*)(W2 + idx * 4);
    if (tid < HID) bs[tid] = b2[tid];
    __syncthreads();

    const int tx = tid & 15, ty = tid >> 4;
    const int j0 = tx * 6, m0 = ty * 4;

    // GEMM1: 64x96 @ 96x96
    float acc[4][6];
#pragma unroll
    for (int i = 0; i < 4; ++i)
#pragma unroll
        for (int jj = 0; jj < 6; ++jj) acc[i][jj] = 0.0f;
#pragma unroll 4
    for (int k = 0; k < HID; ++k) {
        float a[4], w[6];
#pragma unroll
        for (int i = 0; i < 4; ++i) a[i] = in_s[m0 + i][k];
#pragma unroll
        for (int jj = 0; jj < 6; ++jj) w[jj] = W_s[k * HID + j0 + jj];
#pragma unroll
        for (int i = 0; i < 4; ++i)
#pragma unroll
            for (int jj = 0; jj < 6; ++jj) acc[i][jj] += a[i] * w[jj];
    }
    __syncthreads();

    // h2 tile -> in_s (in place); W3 (zero-padded to 64 cols) -> W_s
#pragma unroll
    for (int i = 0; i < 4; ++i) {
        int n = n0 + m0 + i;
        float on = (n < N_NODES) ? out_norm[n] : 0.0f;
#pragma unroll
        for (int jj = 0; jj < 6; ++jj)
            in_s[m0 + i][j0 + jj] = fmaxf(acc[i][jj] + bs[j0 + jj], 0.0f) * on;
    }
    for (int idx = tid; idx < HID * 64; idx += 256) {
        int k = idx >> 6, j = idx & 63;
        W_s[idx] = (j < NLAB) ? W3[k * NLAB + j] : 0.0f;
    }
    __syncthreads();

    // GEMM2: 64x96 @ 96x64 (cols >= 50 zero)
    const int j20 = tx * 4;
    float acc2[4][4];
#pragma unroll
    for (int i = 0; i < 4; ++i)
#pragma unroll
        for (int jj = 0; jj < 4; ++jj) acc2[i][jj] = 0.0f;
#pragma unroll 4
    for (int k = 0; k < HID; ++k) {
        float a[4], w[4];
#pragma unroll
        for (int i = 0; i < 4; ++i) a[i] = in_s[m0 + i][k];
#pragma unroll
        for (int jj = 0; jj < 4; ++jj) w[jj] = W_s[k * 64 + j20 + jj];
#pragma unroll
        for (int i = 0; i < 4; ++i)
#pragma unroll
            for (int jj = 0; jj < 4; ++jj) acc2[i][jj] += a[i] * w[jj];
    }
    if (j20 < 4 * TC) {   // tx <= 12: cols 0..51 (52..63 never read)
#pragma unroll
        for (int i = 0; i < 4; ++i) {
            int n = n0 + m0 + i;
            if (n >= N_NODES) break;
            uint2 raw;
            raw.x = f2h(acc2[i][0], acc2[i][1]);
            raw.y = f2h(acc2[i][2], acc2[i][3]);
            *(uint2*)(t + (size_t)n * TSTRIDE + j20) = raw;
        }
    }
}

// Final gather over FP16 t (128B-aligned rows, 1 line each).
__global__ void gather_out_kernel(const __half* __restrict__ t, const int* __restrict__ row_off,
                                  const int* __restrict__ deg, const int2* __restrict__ erec,
                                  const float* __restrict__ in_norm, const float* __restrict__ bias,
                                  float* __restrict__ out) {
    int i = blockIdx.x * blockDim.x + threadIdx.x;
    if (i >= N_NODES * TC) return;
    int n = i / TC;
    int c = i - n * TC;
    const __half* p0 = t + c * 4;
    int k = row_off[n];
    int e = k + deg[n];
    float ax = 0.f, ay = 0.f, az = 0.f, aw = 0.f;
    for (; k + 3 < e; k += 4) {
        size_t r0 = (size_t)(erec[k].x & 0xFFFF) * TSTRIDE;
        size_t r1 = (size_t)(erec[k + 1].x & 0xFFFF) * TSTRIDE;
        size_t r2 = (size_t)(erec[k + 2].x & 0xFFFF) * TSTRIDE;
        size_t r3 = (size_t)(erec[k + 3].x & 0xFFFF) * TSTRIDE;
        uint2 v0 = *(const uint2*)(p0 + r0);
        uint2 v1 = *(const uint2*)(p0 + r1);
        uint2 v2 = *(const uint2*)(p0 + r2);
        uint2 v3 = *(const uint2*)(p0 + r3);
        float2 f;
        f = h2f(v0.x); ax += f.x; ay += f.y;  f = h2f(v0.y); az += f.x; aw += f.y;
        f = h2f(v1.x); ax += f.x; ay += f.y;  f = h2f(v1.y); az += f.x; aw += f.y;
        f = h2f(v2.x); ax += f.x; ay += f.y;  f = h2f(v2.y); az += f.x; aw += f.y;
        f = h2f(v3.x); ax += f.x; ay += f.y;  f = h2f(v3.y); az += f.x; aw += f.y;
    }
    for (; k < e; ++k) {
        size_t r0 = (size_t)(erec[k].x & 0xFFFF) * TSTRIDE;
        uint2 v0 = *(const uint2*)(p0 + r0);
        float2 f;
        f = h2f(v0.x); ax += f.x; ay += f.y;  f = h2f(v0.y); az += f.x; aw += f.y;
    }
    float nn = in_norm[n];
    int j = c * 4;
    float* op = out + (size_t)n * NLAB + j;   // rows 8B-aligned only -> float2 stores
    float2 lo; lo.x = ax * nn + bias[j];     lo.y = ay * nn + bias[j + 1];
    *(float2*)op = lo;
    if (j + 2 < NLAB) {
        float2 hi; hi.x = az * nn + bias[j + 2]; hi.y = aw * nn + bias[j + 3];
        *(float2*)(op + 2) = hi;
    }
}

static inline int cdiv(long a, int b) { return (int)((a + b - 1) / b); }

extern "C" void kernel_launch(void* const* d_in, const int* in_sizes, int n_in,
                              void* d_out, int out_size, void* d_ws, size_t ws_size,
                              hipStream_t stream) {
    const int*   dep_labels = (const int*)d_in[0];
    const int*   src        = (const int*)d_in[1];
    const int*   dst        = (const int*)d_in[2];
    const float* emb        = (const float*)d_in[3];
    const float* W1 = (const float*)d_in[4]; const float* b1 = (const float*)d_in[5];
    const float* W2 = (const float*)d_in[6]; const float* b2 = (const float*)d_in[7];
    const float* W3 = (const float*)d_in[8]; const float* b3 = (const float*)d_in[9];
    float* out = (float*)d_out;

    // ---- workspace layout (regions kept 128B-aligned) ----
    int* wsp        = (int*)d_ws;
    int* deg_out_i  = wsp;                 wsp += N_NODES;
    int* deg_in_i   = wsp;                 wsp += N_NODES;
    int* row_off    = wsp;                 wsp += N_NODES;
    int* rank       = wsp;                 wsp += N_EDGES;
    int* bsum       = wsp;                 wsp += 256;
    float* out_norm = (float*)wsp;         wsp += N_NODES;
    float* in_norm  = (float*)wsp;         wsp += N_NODES;
    int2* node_info = (int2*)wsp;          wsp += 2 * N_NODES;
    float* T1       = (float*)wsp;         wsp += NLAB * HID + 16;  // pad to 32-int multiple
    int2* edge_rec  = (int2*)wsp;          wsp += 2 * N_EDGES;      // 6.4 MB
    float* bufA     = (float*)wsp;         wsp += (size_t)N_NODES * HID;   // agg (fp32)
    __half* bufH    = (__half*)wsp;        // h1s (fp16), then t (fp16, stride 64)

    const int B = 256;
    const int NLIN = cdiv(N_NODES, 64);    // 782

    hipMemsetAsync(deg_out_i, 0, 2 * N_NODES * sizeof(int), stream);
    deg_rank_t1_kernel<<<EDGEB + T1B, B, 0, stream>>>(src, dst, deg_out_i, deg_in_i, rank,
                                                      emb, W1, T1);

    scan1_kernel<<<NB_SCAN, 256, 0, stream>>>(deg_in_i, bsum);
    scan23_kernel<<<NB_SCAN, 256, 0, stream>>>(deg_in_i, bsum, deg_out_i, dep_labels,
                                               row_off, out_norm, in_norm, node_info);
    fill_kernel<<<EDGEB, B, 0, stream>>>(src, dst, row_off, rank, node_info, edge_rec);

    // Layer 1 fused: linear edge_rec stream, T1 L1-resident -> h1s (fp16)
    gather1t_kernel<<<cdiv((long)N_NODES * (HID / 8), B), B, 0, stream>>>(
        edge_rec, T1, row_off, deg_in_i, in_norm, out_norm, b1, bufH);

    // Layer 2 aggregate (fp16 rows -> fp32 agg)
    gather4x2_kernel<<<cdiv((long)N_NODES * (HID / 8), B), B, 0, stream>>>(
        bufH, row_off, deg_in_i, edge_rec, in_norm, bufA);

    // Layers 2+3 fused transform: agg -> t (fp16 stride 64; h2 stays in LDS)
    linear23_kernel<<<NLIN, 256, 0, stream>>>(bufA, W2, b2, out_norm, W3, bufH);

    // Final gather + bias (fp16 t -> fp32 out)
    gather_out_kernel<<<cdiv((long)N_NODES * TC, B), B, 0, stream>>>(
        bufH, row_off, deg_in_i, edge_rec, in_norm, b3, out);
}